// Round 1
// baseline (135.245 us; speedup 1.0000x reference)
//
#include <hip/hip_runtime.h>
#include <cstdint>

#define TPB 256
#define IT 4        // i-rows per thread -> 1024 rows per block
#define JCHUNK 512  // j-columns staged in LDS per block (8 KiB)

// ---------------------------------------------------------------------------
// Kernel A: compute gt = R*kp + t, |gt|^2; init best-keys and accumulators.
// ---------------------------------------------------------------------------
__global__ void prep_kernel(const float* __restrict__ kp_before,
                            const float* __restrict__ pose,
                            float4* __restrict__ gt4,
                            unsigned long long* __restrict__ best,
                            float* __restrict__ accum,
                            int M, int N) {
    int tid = blockIdx.x * blockDim.x + threadIdx.x;
    if (tid < 8) accum[tid] = 0.0f;
    int stride = gridDim.x * blockDim.x;
    for (int i = tid; i < M; i += stride) {
        best[i] = 0xFFFFFFFFFFFFFFFFULL;
        int b = i / N;
        const float* P = pose + b * 12;
        float k0 = kp_before[3*i+0];
        float k1 = kp_before[3*i+1];
        float k2 = kp_before[3*i+2];
        // FMA chain (ascending k) + t, matching BLAS/XLA contraction order.
        float g0 = fmaf(P[2],  k2, fmaf(P[1], k1, P[0]*k0)) + P[3];
        float g1 = fmaf(P[6],  k2, fmaf(P[5], k1, P[4]*k0)) + P[7];
        float g2 = fmaf(P[10], k2, fmaf(P[9], k1, P[8]*k0)) + P[11];
        float sg;
        {
            #pragma clang fp contract(off)
            sg = (g0*g0 + g1*g1) + g2*g2;   // numpy sum order, no FMA
        }
        gt4[i] = make_float4(g0, g1, g2, sg);
    }
}

// ---------------------------------------------------------------------------
// Kernel B: fused pairwise-distance argmin. Each block owns a (1024-row x
// 512-col) tile; gt columns staged once in LDS; per-thread running best for
// IT rows; cross-chunk combine via u64 atomicMin on (valbits<<32 | j) keys
// (ties -> lowest j, matching np.argmin first-occurrence).
// ---------------------------------------------------------------------------
__global__ void __launch_bounds__(TPB, 2) argmin_kernel(
        const float* __restrict__ pred,
        const float4* __restrict__ gt4,
        unsigned long long* __restrict__ best,
        int M, int numI) {
    __shared__ float4 sh[JCHUNK];
    int ic = blockIdx.x % numI;
    int jc = blockIdx.x / numI;
    int j0 = jc * JCHUNK;
    int jmax = M - j0; if (jmax > JCHUNK) jmax = JCHUNK;

    for (int k = threadIdx.x; k < jmax; k += TPB) {
        sh[k] = gt4[j0 + k];
    }
    __syncthreads();

    float tp0[IT], tp1[IT], tp2[IT], sp[IT], bv[IT];
    int bi[IT];
    int ibase = ic * (TPB * IT) + threadIdx.x;
    #pragma unroll
    for (int k = 0; k < IT; k++) {
        int i = ibase + k * TPB;
        if (i >= M) i = M - 1;  // safe dup (M divisible in practice)
        float p0 = pred[3*i+0], p1 = pred[3*i+1], p2 = pred[3*i+2];
        {
            #pragma clang fp contract(off)
            sp[k] = (p0*p0 + p1*p1) + p2*p2;   // numpy sum order
        }
        tp0[k] = 2.0f * p0;  // exact scaling: 2*dot is rounding-exact
        tp1[k] = 2.0f * p1;
        tp2[k] = 2.0f * p2;
        bv[k] = __uint_as_float(0x7f7fffffu);  // FLT_MAX
        bi[k] = 0;
    }

    for (int j = 0; j < jmax; j++) {
        float4 g = sh[j];
        int gj = j0 + j;
        #pragma unroll
        for (int k = 0; k < IT; k++) {
            // 2*(p . g) as FMA chain == 2 * (BLAS fma dot), bitwise
            float dot2 = fmaf(tp2[k], g.z, fmaf(tp1[k], g.y, tp0[k] * g.x));
            float v = (sp[k] + g.w) - dot2;    // (sp+sg) - 2*dot, ref order
            v = fmaxf(v, 0.0f);                // maximum(sq, 0)
            if (v < bv[k]) { bv[k] = v; bi[k] = gj; }  // strict < keeps first
        }
    }

    #pragma unroll
    for (int k = 0; k < IT; k++) {
        int i = ibase + k * TPB;
        if (i >= M) continue;
        unsigned int ub = __float_as_uint(bv[k]);
        if (ub == 0x80000000u) ub = 0u;        // canonicalize -0.0
        unsigned long long key =
            ((unsigned long long)ub << 32) | (unsigned int)bi[k];
        atomicMin(&best[i], key);
    }
}

// ---------------------------------------------------------------------------
// Kernel C: per-point BCE (balanced groups) + weighted L1 error; block/wave
// reduce then atomicAdd into accum[6].
// accum: [0]=sum(w*err) [1]=sum(w) [2]=sum bce|label1 [3]=cnt1
//        [4]=sum bce|label0 [5]=cnt0
// ---------------------------------------------------------------------------
__device__ inline float wave_red(float v) {
    #pragma unroll
    for (int off = 32; off > 0; off >>= 1) v += __shfl_down(v, off, 64);
    return v;
}

__global__ void finalize_kernel(const float* __restrict__ pred,
                                const float4* __restrict__ gt4,
                                const float* __restrict__ ow,
                                const float* __restrict__ logits,
                                const unsigned long long* __restrict__ best,
                                float* __restrict__ accum, int M) {
    float werr = 0.f, wsum = 0.f, b1 = 0.f, c1 = 0.f, b0 = 0.f, c0 = 0.f;
    int stride = gridDim.x * blockDim.x;
    for (int i = blockIdx.x * blockDim.x + threadIdx.x; i < M; i += stride) {
        unsigned int idx = (unsigned int)(best[i] & 0xFFFFFFFFULL);
        float x = logits[i];
        float l1p = log1pf(expf(-fabsf(x)));   // softplus tail
        if (idx == (unsigned int)i) {          // label 1: bce = softplus(-x)
            b1 += fmaxf(-x, 0.f) + l1p; c1 += 1.f;
        } else {                               // label 0: bce = softplus(x)
            b0 += fmaxf(x, 0.f) + l1p;  c0 += 1.f;
        }
        float4 g = gt4[i];
        float p0 = pred[3*i+0], p1 = pred[3*i+1], p2 = pred[3*i+2];
        float e = (fabsf(p0 - g.x) + fabsf(p1 - g.y)) + fabsf(p2 - g.z);
        float wi = ow[i];
        werr += wi * e;
        wsum += wi;
    }
    werr = wave_red(werr); wsum = wave_red(wsum);
    b1 = wave_red(b1); c1 = wave_red(c1);
    b0 = wave_red(b0); c0 = wave_red(c0);
    if ((threadIdx.x & 63) == 0) {
        atomicAdd(&accum[0], werr);
        atomicAdd(&accum[1], wsum);
        atomicAdd(&accum[2], b1);
        atomicAdd(&accum[3], c1);
        atomicAdd(&accum[4], b0);
        atomicAdd(&accum[5], c0);
    }
}

// ---------------------------------------------------------------------------
// Kernel D: final scalar combine.
// ---------------------------------------------------------------------------
__global__ void scalar_kernel(const float* __restrict__ accum,
                              float* __restrict__ out) {
    float mean_err = accum[0] / fmaxf(accum[1], 1e-6f);
    float g1 = (accum[3] > 0.f) ? (accum[2] / fmaxf(accum[3], 1.f)) : 0.f;
    float g0 = (accum[5] > 0.f) ? (accum[4] / fmaxf(accum[5], 1.f)) : 0.f;
    out[0] = mean_err + (g0 * 0.5f + g1 * 0.5f);
}

extern "C" void kernel_launch(void* const* d_in, const int* in_sizes, int n_in,
                              void* d_out, int out_size, void* d_ws, size_t ws_size,
                              hipStream_t stream) {
    const float* kp_before = (const float*)d_in[0];
    const float* pred      = (const float*)d_in[1];
    const float* pose      = (const float*)d_in[2];
    const float* ow        = (const float*)d_in[3];
    const float* logits    = (const float*)d_in[4];
    float* out = (float*)d_out;

    int M = in_sizes[3];            // B*N = 16384
    int B = in_sizes[2] / 12;       // 2
    int N = M / B;                  // 8192

    char* ws = (char*)d_ws;
    float4* gt4 = (float4*)ws;                                     // M*16 B
    unsigned long long* best =
        (unsigned long long*)(ws + (size_t)M * 16);                // M*8 B
    float* accum = (float*)(ws + (size_t)M * 16 + (size_t)M * 8);  // 32 B

    int prep_blocks = (M + TPB - 1) / TPB;                         // 64
    hipLaunchKernelGGL(prep_kernel, dim3(prep_blocks), dim3(TPB), 0, stream,
                       kp_before, pose, gt4, best, accum, M, N);

    int numI = (M + TPB * IT - 1) / (TPB * IT);                    // 16
    int numJ = (M + JCHUNK - 1) / JCHUNK;                          // 32
    hipLaunchKernelGGL(argmin_kernel, dim3(numI * numJ), dim3(TPB), 0, stream,
                       pred, gt4, best, M, numI);

    hipLaunchKernelGGL(finalize_kernel, dim3(64), dim3(TPB), 0, stream,
                       pred, gt4, ow, logits, best, accum, M);

    hipLaunchKernelGGL(scalar_kernel, dim3(1), dim3(1), 0, stream,
                       accum, out);
}

// Round 2
// 122.558 us; speedup vs baseline: 1.1035x; 1.1035x over previous
//
#include <hip/hip_runtime.h>
#include <cstdint>

#define TPB 256
#define IT 8        // i-rows per thread -> 2048 rows per block
#define JCHUNK 64   // j-columns staged in LDS per block (1 KiB)

// ---------------------------------------------------------------------------
// Kernel A: gt = R*kp + t, |gt|^2; thr[i] = clamped self-distance d(i,i);
// zero good-counters and accumulators.
// All arithmetic bit-matches the numpy reference (validated absmax=0.0 in R1):
// dot via ascending-k FMA chain, sums via (a+b)+c with contraction off,
// 2*dot via pre-scaled operands (exact).
// ---------------------------------------------------------------------------
__global__ void prep_kernel(const float* __restrict__ kp_before,
                            const float* __restrict__ pred,
                            const float* __restrict__ pose,
                            float4* __restrict__ gt4,
                            float* __restrict__ thr,
                            unsigned int* __restrict__ good,
                            float* __restrict__ accum,
                            int M, int N) {
    int tid = blockIdx.x * blockDim.x + threadIdx.x;
    if (tid < 8) accum[tid] = 0.0f;
    int stride = gridDim.x * blockDim.x;
    for (int i = tid; i < M; i += stride) {
        good[i] = 0u;
        int b = i / N;
        const float* P = pose + b * 12;
        float k0 = kp_before[3*i+0];
        float k1 = kp_before[3*i+1];
        float k2 = kp_before[3*i+2];
        float g0 = fmaf(P[2],  k2, fmaf(P[1], k1, P[0]*k0)) + P[3];
        float g1 = fmaf(P[6],  k2, fmaf(P[5], k1, P[4]*k0)) + P[7];
        float g2 = fmaf(P[10], k2, fmaf(P[9], k1, P[8]*k0)) + P[11];
        float sg;
        {
            #pragma clang fp contract(off)
            sg = (g0*g0 + g1*g1) + g2*g2;   // numpy sum order, no FMA
        }
        gt4[i] = make_float4(g0, g1, g2, sg);

        // self-distance threshold, identical op sequence to the main loop
        float p0 = pred[3*i+0], p1 = pred[3*i+1], p2 = pred[3*i+2];
        float sp;
        {
            #pragma clang fp contract(off)
            sp = (p0*p0 + p1*p1) + p2*p2;
        }
        float t0 = 2.0f*p0, t1 = 2.0f*p1, t2 = 2.0f*p2;
        float dot2 = fmaf(t2, g2, fmaf(t1, g1, t0*g0));
        float v = (sp + sg) - dot2;
        thr[i] = fmaxf(v, 0.0f);
    }
}

// ---------------------------------------------------------------------------
// Kernel B: per-(row, j-chunk) "good" flags. mask[i]=1 iff argmin_j d(i,j)==i
// (first-occurrence ties), i.e. no j<i with d<=d_ii and no j>i with d<d_ii.
// Inner loop is a pure fmin reduction (clamp + compare hoisted out); chunks
// entirely left of the diagonal use <= at the end, others use < plus an exact
// equality fixup scan for the (rare) lanes whose i lies inside the chunk.
// ---------------------------------------------------------------------------
__global__ void __launch_bounds__(TPB, 8) flags_kernel(
        const float* __restrict__ pred,
        const float4* __restrict__ gt4,
        const float* __restrict__ thr,
        unsigned int* __restrict__ good,
        int M, int numI) {
    __shared__ float4 sh[JCHUNK];
    int ic = blockIdx.x % numI;
    int jc = blockIdx.x / numI;
    int j0 = jc * JCHUNK;
    int jmax = M - j0; if (jmax > JCHUNK) jmax = JCHUNK;

    for (int k = threadIdx.x; k < jmax; k += TPB) {
        sh[k] = gt4[j0 + k];
    }
    __syncthreads();

    float tp0[IT], tp1[IT], tp2[IT], sp[IT], m[IT];
    int ibase = ic * (TPB * IT) + threadIdx.x;
    #pragma unroll
    for (int k = 0; k < IT; k++) {
        int i = ibase + k * TPB;
        if (i >= M) i = M - 1;
        float p0 = pred[3*i+0], p1 = pred[3*i+1], p2 = pred[3*i+2];
        {
            #pragma clang fp contract(off)
            sp[k] = (p0*p0 + p1*p1) + p2*p2;
        }
        tp0[k] = 2.0f * p0;
        tp1[k] = 2.0f * p1;
        tp2[k] = 2.0f * p2;
        m[k] = __uint_as_float(0x7f7fffffu);  // FLT_MAX
    }

    int j = 0;
    for (; j + 1 < jmax; j += 2) {
        float4 ga = sh[j];
        float4 gb = sh[j + 1];
        #pragma unroll
        for (int k = 0; k < IT; k++) {
            float va = (sp[k] + ga.w) -
                       fmaf(tp2[k], ga.z, fmaf(tp1[k], ga.y, tp0[k] * ga.x));
            float vb = (sp[k] + gb.w) -
                       fmaf(tp2[k], gb.z, fmaf(tp1[k], gb.y, tp0[k] * gb.x));
            m[k] = fminf(fminf(va, vb), m[k]);   // -> v_min3_f32
        }
    }
    if (j < jmax) {
        float4 ga = sh[j];
        #pragma unroll
        for (int k = 0; k < IT; k++) {
            float va = (sp[k] + ga.w) -
                       fmaf(tp2[k], ga.z, fmaf(tp1[k], ga.y, tp0[k] * ga.x));
            m[k] = fminf(va, m[k]);
        }
    }

    int j1 = j0 + jmax;
    #pragma unroll
    for (int k = 0; k < IT; k++) {
        int i = ibase + k * TPB;
        if (i >= M) continue;
        float dii = thr[i];
        float vminc = fmaxf(m[k], 0.0f);   // clamp commutes with min
        bool bad;
        if (i >= j1) {
            bad = (vminc <= dii);          // whole chunk is j < i
        } else {
            bad = (vminc < dii);           // strict part (covers j >= i, j==i)
            if (!bad && i > j0) {
                // exact equality fixup for j in [j0, min(i, j1))
                int je = i < j1 ? (i - j0) : jmax;  // i<j1 here, so i-j0
                for (int jj = 0; jj < je; jj++) {
                    float4 g = sh[jj];
                    float v = (sp[k] + g.w) -
                              fmaf(tp2[k], g.z, fmaf(tp1[k], g.y, tp0[k] * g.x));
                    if (fmaxf(v, 0.0f) <= dii) { bad = true; break; }
                }
            }
        }
        if (!bad) atomicAdd(&good[i], 1u);   // rare (~1/(JCHUNK+1))
    }
}

// ---------------------------------------------------------------------------
// Kernel C: per-point BCE (balanced groups) + weighted L1; wave reduce then
// atomicAdd into accum[6].
// ---------------------------------------------------------------------------
__device__ inline float wave_red(float v) {
    #pragma unroll
    for (int off = 32; off > 0; off >>= 1) v += __shfl_down(v, off, 64);
    return v;
}

__global__ void finalize_kernel(const float* __restrict__ pred,
                                const float4* __restrict__ gt4,
                                const float* __restrict__ ow,
                                const float* __restrict__ logits,
                                const unsigned int* __restrict__ good,
                                float* __restrict__ accum, int M, int numJ) {
    float werr = 0.f, wsum = 0.f, b1 = 0.f, c1 = 0.f, b0 = 0.f, c0 = 0.f;
    int stride = gridDim.x * blockDim.x;
    for (int i = blockIdx.x * blockDim.x + threadIdx.x; i < M; i += stride) {
        float x = logits[i];
        float l1p = log1pf(expf(-fabsf(x)));   // softplus tail
        if (good[i] == (unsigned int)numJ) {   // label 1: bce = softplus(-x)
            b1 += fmaxf(-x, 0.f) + l1p; c1 += 1.f;
        } else {                               // label 0: bce = softplus(x)
            b0 += fmaxf(x, 0.f) + l1p;  c0 += 1.f;
        }
        float4 g = gt4[i];
        float p0 = pred[3*i+0], p1 = pred[3*i+1], p2 = pred[3*i+2];
        float e = (fabsf(p0 - g.x) + fabsf(p1 - g.y)) + fabsf(p2 - g.z);
        float wi = ow[i];
        werr += wi * e;
        wsum += wi;
    }
    werr = wave_red(werr); wsum = wave_red(wsum);
    b1 = wave_red(b1); c1 = wave_red(c1);
    b0 = wave_red(b0); c0 = wave_red(c0);
    if ((threadIdx.x & 63) == 0) {
        atomicAdd(&accum[0], werr);
        atomicAdd(&accum[1], wsum);
        atomicAdd(&accum[2], b1);
        atomicAdd(&accum[3], c1);
        atomicAdd(&accum[4], b0);
        atomicAdd(&accum[5], c0);
    }
}

// ---------------------------------------------------------------------------
// Kernel D: final scalar combine.
// ---------------------------------------------------------------------------
__global__ void scalar_kernel(const float* __restrict__ accum,
                              float* __restrict__ out) {
    float mean_err = accum[0] / fmaxf(accum[1], 1e-6f);
    float g1 = (accum[3] > 0.f) ? (accum[2] / fmaxf(accum[3], 1.f)) : 0.f;
    float g0 = (accum[5] > 0.f) ? (accum[4] / fmaxf(accum[5], 1.f)) : 0.f;
    out[0] = mean_err + (g0 * 0.5f + g1 * 0.5f);
}

extern "C" void kernel_launch(void* const* d_in, const int* in_sizes, int n_in,
                              void* d_out, int out_size, void* d_ws, size_t ws_size,
                              hipStream_t stream) {
    const float* kp_before = (const float*)d_in[0];
    const float* pred      = (const float*)d_in[1];
    const float* pose      = (const float*)d_in[2];
    const float* ow        = (const float*)d_in[3];
    const float* logits    = (const float*)d_in[4];
    float* out = (float*)d_out;

    int M = in_sizes[3];            // B*N = 16384
    int B = in_sizes[2] / 12;       // 2
    int N = M / B;                  // 8192

    char* ws = (char*)d_ws;
    float4* gt4 = (float4*)ws;                                  // M*16 B
    float* thr = (float*)(ws + (size_t)M * 16);                 // M*4 B
    unsigned int* good = (unsigned int*)(ws + (size_t)M * 20);  // M*4 B
    float* accum = (float*)(ws + (size_t)M * 24);               // 32 B

    int prep_blocks = (M + TPB - 1) / TPB;                      // 64
    hipLaunchKernelGGL(prep_kernel, dim3(prep_blocks), dim3(TPB), 0, stream,
                       kp_before, pred, pose, gt4, thr, good, accum, M, N);

    int numI = (M + TPB * IT - 1) / (TPB * IT);                 // 8
    int numJ = (M + JCHUNK - 1) / JCHUNK;                       // 256
    hipLaunchKernelGGL(flags_kernel, dim3(numI * numJ), dim3(TPB), 0, stream,
                       pred, gt4, thr, good, M, numI);

    hipLaunchKernelGGL(finalize_kernel, dim3(64), dim3(TPB), 0, stream,
                       pred, gt4, ow, logits, good, accum, M, numJ);

    hipLaunchKernelGGL(scalar_kernel, dim3(1), dim3(1), 0, stream,
                       accum, out);
}